// Round 2
// baseline (893.772 us; speedup 1.0000x reference)
//
#include <hip/hip_runtime.h>

// Problem constants (fixed by the reference file).
#define BN 2
#define NN 50000
#define EE 500000
#define DD 128
#define OO 128

typedef __attribute__((ext_vector_type(8))) __bf16 bf16x8;
typedef __attribute__((ext_vector_type(4))) float f32x4;

// ---------------------------------------------------------------------------
// cvt8: 8 fp32 -> int4 of packed bf16-hi + int4 of packed bf16-lo (residual).
// Split is exact: v = hi + lo + O(2^-14 * v). (col 2i -> low 16b, 2i+1 -> high)
// ---------------------------------------------------------------------------
__device__ __forceinline__ void cvt8(const f32x4 a, const f32x4 b,
                                     int4& hi, int4& lo) {
    const float v[8] = {a[0], a[1], a[2], a[3], b[0], b[1], b[2], b[3]};
    unsigned int hw[4], lw[4];
#pragma unroll
    for (int i = 0; i < 4; ++i) {
        const unsigned int b0 = __float_as_uint(v[2 * i]);
        const unsigned int b1 = __float_as_uint(v[2 * i + 1]);
        const float r0 = v[2 * i]     - __uint_as_float(b0 & 0xffff0000u);
        const float r1 = v[2 * i + 1] - __uint_as_float(b1 & 0xffff0000u);
        hw[i] = (b0 >> 16) | (b1 & 0xffff0000u);
        lw[i] = (__float_as_uint(r0) >> 16) | (__float_as_uint(r1) & 0xffff0000u);
    }
    hi = make_int4(hw[0], hw[1], hw[2], hw[3]);
    lo = make_int4(lw[0], lw[1], lw[2], lw[3]);
}

// ---------------------------------------------------------------------------
// Wf = W_msg @ W_upd (384x128) computed in fp32, split to bf16 hi/lo, written
// directly in per-lane MFMA B-fragment layout:
//   idx = ((kstep*8 + coltile)*64 + lane)*8 + e
//   lane = (k%32/8)*16 + (o%16), e = k%8, kstep = k/32, coltile = o/16
// ---------------------------------------------------------------------------
__global__ __launch_bounds__(128) void wfuse_k(
    const float* __restrict__ Wm, const float* __restrict__ Wu,
    const float* __restrict__ bm, unsigned short* __restrict__ Wph,
    unsigned short* __restrict__ Wpl, float* __restrict__ bmu) {
    const int o = threadIdx.x;
    const int k = blockIdx.x;
    float s = 0.0f;
    if (k < 3 * DD) {
#pragma unroll 4
        for (int j = 0; j < OO; ++j) s += Wm[k * OO + j] * Wu[j * OO + o];
        const unsigned int u = __float_as_uint(s);
        const unsigned short hi = (unsigned short)(u >> 16);
        const float r = s - __uint_as_float(u & 0xffff0000u);
        const unsigned short lo = (unsigned short)(__float_as_uint(r) >> 16);
        const int kstep = k >> 5;
        const int kr = k & 31;
        const int lane = (kr >> 3) * 16 + (o & 15);
        const int ct = o >> 4;
        const int idx = (((kstep * 8) + ct) * 64 + lane) * 8 + (kr & 7);
        Wph[idx] = hi;
        Wpl[idx] = lo;
    } else {
#pragma unroll 4
        for (int j = 0; j < OO; ++j) s += bm[j] * Wu[j * OO + o];
        bmu[o] = s;
    }
}

// ---------------------------------------------------------------------------
// CSR build: histogram -> 3-phase parallel scan -> fill (packed int2).
// ---------------------------------------------------------------------------
__global__ __launch_bounds__(256) void hist_k(const int* __restrict__ ei,
                                              int* __restrict__ hist) {
    int gid = blockIdx.x * 256 + threadIdx.x;
    if (gid >= EE) return;
    atomicAdd(&hist[ei[EE + gid]], 1);
}

__global__ __launch_bounds__(256) void scan1_k(const int* __restrict__ hist,
                                               int* __restrict__ bsum) {
    int i = blockIdx.x * 256 + threadIdx.x;
    int v = (i < NN) ? hist[i] : 0;
#pragma unroll
    for (int off = 32; off > 0; off >>= 1) v += __shfl_down(v, off);
    __shared__ int ws[4];
    if ((threadIdx.x & 63) == 0) ws[threadIdx.x >> 6] = v;
    __syncthreads();
    if (threadIdx.x == 0) bsum[blockIdx.x] = ws[0] + ws[1] + ws[2] + ws[3];
}

__global__ __launch_bounds__(256) void scan2_k(const int* __restrict__ bsum,
                                               int* __restrict__ ebsum,
                                               int* __restrict__ offsets,
                                               int nblk) {
    __shared__ int s[256];
    const int t = threadIdx.x;
    int v = (t < nblk) ? bsum[t] : 0;
    s[t] = v;
    __syncthreads();
    for (int off = 1; off < 256; off <<= 1) {
        int u = (t >= off) ? s[t - off] : 0;
        __syncthreads();
        s[t] += u;
        __syncthreads();
    }
    ebsum[t] = s[t] - v;
    if (t == 0) offsets[NN] = EE;
}

__global__ __launch_bounds__(256) void scan3_k(const int* __restrict__ hist,
                                               const int* __restrict__ ebsum,
                                               int* __restrict__ offsets,
                                               int* __restrict__ cursor) {
    __shared__ int s[256];
    const int t = threadIdx.x;
    const int i = blockIdx.x * 256 + t;
    int v = (i < NN) ? hist[i] : 0;
    s[t] = v;
    __syncthreads();
    for (int off = 1; off < 256; off <<= 1) {
        int u = (t >= off) ? s[t - off] : 0;
        __syncthreads();
        s[t] += u;
        __syncthreads();
    }
    int ex = s[t] - v + ebsum[blockIdx.x];
    if (i < NN) { offsets[i] = ex; cursor[i] = ex; }
}

__global__ __launch_bounds__(256) void fill_k(const int* __restrict__ ei,
                                              int* __restrict__ cursor,
                                              int2* __restrict__ ep) {
    int gid = blockIdx.x * 256 + threadIdx.x;
    if (gid >= EE) return;
    int dst = ei[EE + gid];
    int pos = atomicAdd(&cursor[dst], 1);
    ep[pos] = make_int2(gid, ei[gid]);
}

// ---------------------------------------------------------------------------
// Degree counting sort (descending): blocks of the fused kernel get
// equal-degree nodes, so block time ~ mean degree, not max over 32 nodes.
// Per-node FP summation order is unchanged -> identical numerics.
// ---------------------------------------------------------------------------
__global__ __launch_bounds__(256) void dhist_k(const int* __restrict__ hist,
                                               int* __restrict__ hist2) {
    int i = blockIdx.x * 256 + threadIdx.x;
    if (i >= NN) return;
    int d = hist[i]; d = d > 63 ? 63 : d;
    atomicAdd(&hist2[63 - d], 1);
}

__global__ __launch_bounds__(64) void dscan_k(const int* __restrict__ hist2,
                                              int* __restrict__ cur2) {
    const int t = threadIdx.x;  // one wave, 64 bins
    int v = hist2[t];
    int s = v;
#pragma unroll
    for (int off = 1; off < 64; off <<= 1) {
        int u = __shfl_up(s, off);
        if (t >= off) s += u;
    }
    cur2[t] = s - v;  // exclusive
}

__global__ __launch_bounds__(256) void dplace_k(const int* __restrict__ hist,
                                                int* __restrict__ cur2,
                                                int* __restrict__ perm) {
    int i = blockIdx.x * 256 + threadIdx.x;
    if (i >= NN) return;
    int d = hist[i]; d = d > 63 ? 63 : d;
    int pos = atomicAdd(&cur2[63 - d], 1);
    perm[pos] = i;
}

// ---------------------------------------------------------------------------
// Fused aggregate + MFMA GEMM.
//   out = diag(1/max(c,1)) * ([S | c*x | T] @ Wf) + (c>0)*bmu + bu
// Block = 32 nodes (degree-sorted via perm) x 2 batches = 64 A-rows.
// Thread (srow = tid>>2, q = tid&3): owns 32 cols of its (batch,node) row.
//   Phase 1 (aggregate, in regs): sA = sum x[b, src] slice (8 f32x4);
//     tp = sum ea slice over its 16-col half (batch0: left, batch1: right)
//     -> per-edge work identical for every thread (8 + 4 float4 loads).
//   Phase 2: stage seg0(S) / seg1(c*x, prefetched) / seg2(T: each thread
//     writes its half to BOTH batch rows) as split-bf16 into swizzled LDS,
//     3 MFMA terms (Ah*Wh + Al*Wh + Ah*Wl) per k-step. Same verified
//     staging/swizzle/fragment machinery as the round-1 gemm_k.
// ---------------------------------------------------------------------------
__global__ __launch_bounds__(256, 3) void fused_k(
    const float* __restrict__ x,
    const float* __restrict__ ea,
    const int* __restrict__ offsets,
    const int2* __restrict__ ep,
    const int* __restrict__ perm,
    const unsigned short* __restrict__ Wph,
    const unsigned short* __restrict__ Wpl,
    const float* __restrict__ bmu,
    const float* __restrict__ bu,
    float* __restrict__ out)
{
    __shared__ unsigned short Ahi[64 * 128];  // 16 KB
    __shared__ unsigned short Alo[64 * 128];  // 16 KB
    __shared__ float cntS[32];
    __shared__ int nidS[32];

    const int tid = threadIdx.x;
    const int srow = tid >> 2;   // 0..63 local A-row
    const int q = tid & 3;       // col quarter (32 floats)
    const int b = srow >> 5;     // batch
    const int i = srow & 31;     // local node
    const int idx = blockIdx.x * 32 + i;
    const bool nv = idx < NN;
    const int n = nv ? perm[idx] : 0;
    const int beg = nv ? offsets[n] : 0;
    const int end = nv ? offsets[n + 1] : 0;
    if (b == 0 && q == 0) { cntS[i] = (float)(end - beg); nidS[i] = n; }

    const float* xb = x + (size_t)(b ? NN : 0) * DD;

    f32x4 sA[8], tp[4];
#pragma unroll
    for (int f = 0; f < 8; ++f) sA[f] = (f32x4){0, 0, 0, 0};
#pragma unroll
    for (int f = 0; f < 4; ++f) tp[f] = (f32x4){0, 0, 0, 0};

    int j = beg;
    for (; j + 1 < end; j += 2) {
        const int2 p0 = ep[j], p1 = ep[j + 1];
        const f32x4* x0 = (const f32x4*)(xb + (size_t)p0.y * DD) + q * 8;
        const f32x4* x1 = (const f32x4*)(xb + (size_t)p1.y * DD) + q * 8;
        const f32x4* e0 = (const f32x4*)(ea + (size_t)p0.x * DD) + q * 8 + b * 4;
        const f32x4* e1 = (const f32x4*)(ea + (size_t)p1.x * DD) + q * 8 + b * 4;
#pragma unroll
        for (int f = 0; f < 8; ++f) sA[f] += x0[f];
#pragma unroll
        for (int f = 0; f < 4; ++f) tp[f] += e0[f];
#pragma unroll
        for (int f = 0; f < 8; ++f) sA[f] += x1[f];
#pragma unroll
        for (int f = 0; f < 4; ++f) tp[f] += e1[f];
    }
    if (j < end) {
        const int2 p = ep[j];
        const f32x4* x0 = (const f32x4*)(xb + (size_t)p.y * DD) + q * 8;
        const f32x4* e0 = (const f32x4*)(ea + (size_t)p.x * DD) + q * 8 + b * 4;
#pragma unroll
        for (int f = 0; f < 8; ++f) sA[f] += x0[f];
#pragma unroll
        for (int f = 0; f < 4; ++f) tp[f] += e0[f];
    }

    // prefetch seg1 source (x[b,n] slice) before mfma(seg0) hides its latency
    const f32x4* xs = (const f32x4*)(xb + (size_t)n * DD) + q * 8;
    f32x4 xv[8];
#pragma unroll
    for (int f = 0; f < 8; ++f) xv[f] = xs[f];

    const int rowb = srow * 256;
    const int swz = (srow & 7) << 4;

    // ---- stage seg0 (S) ----
#pragma unroll
    for (int h = 0; h < 4; ++h) {
        int4 hi, lo;
        cvt8(sA[2 * h], sA[2 * h + 1], hi, lo);
        const int byt = rowb + ((q * 64 + h * 16) ^ swz);
        *(int4*)((char*)Ahi + byt) = hi;
        *(int4*)((char*)Alo + byt) = lo;
    }

    const int wv = tid >> 6;
    const int l = tid & 63;

    f32x4 acc[4][2];
#pragma unroll
    for (int rt = 0; rt < 4; ++rt) {
        acc[rt][0] = (f32x4){0, 0, 0, 0};
        acc[rt][1] = (f32x4){0, 0, 0, 0};
    }

    auto mfma_seg = [&](const int seg) {
#pragma unroll
        for (int ks = 0; ks < 4; ++ks) {
            bf16x8 ah[4], al[4];
#pragma unroll
            for (int rt = 0; rt < 4; ++rt) {
                const int row = rt * 16 + (l & 15);
                const int rb = row * 256 +
                               ((ks * 64 + (l >> 4) * 16) ^ ((row & 7) << 4));
                ah[rt] = *(const bf16x8*)((const char*)Ahi + rb);
                al[rt] = *(const bf16x8*)((const char*)Alo + rb);
            }
            const int kg = seg * 4 + ks;
#pragma unroll
            for (int ct = 0; ct < 2; ++ct) {
                const size_t fi =
                    (size_t)(((kg * 8) + (wv * 2 + ct)) * 64 + l) * 8;
                const bf16x8 wh = *(const bf16x8*)(Wph + fi);
                const bf16x8 wl = *(const bf16x8*)(Wpl + fi);
#pragma unroll
                for (int rt = 0; rt < 4; ++rt) {
                    acc[rt][ct] = __builtin_amdgcn_mfma_f32_16x16x32_bf16(
                        ah[rt], wh, acc[rt][ct], 0, 0, 0);
                    acc[rt][ct] = __builtin_amdgcn_mfma_f32_16x16x32_bf16(
                        al[rt], wh, acc[rt][ct], 0, 0, 0);
                    acc[rt][ct] = __builtin_amdgcn_mfma_f32_16x16x32_bf16(
                        ah[rt], wl, acc[rt][ct], 0, 0, 0);
                }
            }
        }
    };

    __syncthreads();
    mfma_seg(0);
    __syncthreads();

    // ---- stage seg1 (c * x[b,n]) ----
    {
        const float c = (float)(end - beg);
#pragma unroll
        for (int h = 0; h < 4; ++h) {
            int4 hi, lo;
            cvt8(xv[2 * h] * c, xv[2 * h + 1] * c, hi, lo);
            const int byt = rowb + ((q * 64 + h * 16) ^ swz);
            *(int4*)((char*)Ahi + byt) = hi;
            *(int4*)((char*)Alo + byt) = lo;
        }
    }
    __syncthreads();
    mfma_seg(1);
    __syncthreads();

    // ---- stage seg2 (T): thread writes its 16-col half to BOTH batch rows ----
    {
        const int colb = q * 64 + b * 32;
        const int r0 = i * 256;
        const int r1 = (i + 32) * 256;
        const int sz = (i & 7) << 4;  // (i)&7 == (i+32)&7 -> same swizzle
#pragma unroll
        for (int h = 0; h < 2; ++h) {
            int4 hi, lo;
            cvt8(tp[2 * h], tp[2 * h + 1], hi, lo);
            const int cb = (colb + h * 16) ^ sz;
            *(int4*)((char*)Ahi + r0 + cb) = hi;
            *(int4*)((char*)Alo + r0 + cb) = lo;
            *(int4*)((char*)Ahi + r1 + cb) = hi;
            *(int4*)((char*)Alo + r1 + cb) = lo;
        }
    }
    __syncthreads();
    mfma_seg(2);

    // ---- epilogue ----
    const int col0 = wv * 32 + (l & 15);
    const float bm0 = bmu[col0], bm1 = bmu[col0 + 16];
    const float bu0 = bu[col0], bu1 = bu[col0 + 16];
    const int rbase = (l >> 4) * 4;
#pragma unroll
    for (int rt = 0; rt < 4; ++rt) {
#pragma unroll
        for (int r = 0; r < 4; ++r) {
            const int lr = rt * 16 + rbase + r;
            const int li = lr & 31;
            if (blockIdx.x * 32 + li < NN) {
                const int lb = lr >> 5;
                const int nn = nidS[li];
                const float cc = cntS[li];
                const float inv = 1.0f / fmaxf(cc, 1.0f);
                const float g = (cc > 0.0f) ? 1.0f : 0.0f;
                const size_t R = (size_t)(lb ? NN : 0) + nn;
                __builtin_nontemporal_store(
                    acc[rt][0][r] * inv + g * bm0 + bu0,
                    out + R * OO + col0);
                __builtin_nontemporal_store(
                    acc[rt][1][r] * inv + g * bm1 + bu1,
                    out + R * OO + col0 + 16);
            }
        }
    }
}

extern "C" void kernel_launch(void* const* d_in, const int* in_sizes, int n_in,
                              void* d_out, int out_size, void* d_ws, size_t ws_size,
                              hipStream_t stream) {
    const float* x  = (const float*)d_in[0];
    const int*   ei = (const int*)d_in[1];
    const float* ea = (const float*)d_in[2];
    const float* Wm = (const float*)d_in[3];
    const float* bm = (const float*)d_in[4];
    const float* Wu = (const float*)d_in[5];
    const float* bu = (const float*)d_in[6];
    float* out = (float*)d_out;

    // workspace layout (ints counted so ep stays 8B-aligned)
    unsigned short* Wph = (unsigned short*)d_ws;      //  49,152 us
    unsigned short* Wpl = Wph + 3 * DD * OO;          //  49,152 us
    float* bmu   = (float*)(Wpl + 3 * DD * OO);       //     128 f
    int* offsets = (int*)(bmu + OO);                  //  50,004 i
    int* cursor  = offsets + 50004;                   //  50,000 i
    int* hist    = cursor + NN;                       //  50,000 i
    int* hist2   = hist + NN;                         //      64 i
    int* cur2    = hist2 + 64;                        //      64 i
    int* perm    = cur2 + 64;                         //  50,000 i
    int* bsum    = perm + NN;                         //     256 i
    int* ebsum   = bsum + 256;                        //     256 i
    int2* ep     = (int2*)(ebsum + 256);              // 500,000 int2

    const int nscan = (NN + 255) / 256;               // 196

    // zero hist + hist2 in one shot (contiguous)
    hipMemsetAsync(hist, 0, (NN + 64) * sizeof(int), stream);

    wfuse_k<<<3 * DD + 1, 128, 0, stream>>>(Wm, Wu, bm, Wph, Wpl, bmu);
    hist_k<<<(EE + 255) / 256, 256, 0, stream>>>(ei, hist);
    scan1_k<<<nscan, 256, 0, stream>>>(hist, bsum);
    scan2_k<<<1, 256, 0, stream>>>(bsum, ebsum, offsets, nscan);
    scan3_k<<<nscan, 256, 0, stream>>>(hist, ebsum, offsets, cursor);
    dhist_k<<<nscan, 256, 0, stream>>>(hist, hist2);
    dscan_k<<<1, 64, 0, stream>>>(hist2, cur2);
    dplace_k<<<nscan, 256, 0, stream>>>(hist, cur2, perm);
    fill_k<<<(EE + 255) / 256, 256, 0, stream>>>(ei, cursor, ep);

    const int nblocks = (NN + 31) / 32;               // 1563
    fused_k<<<nblocks, 256, 0, stream>>>(x, ea, offsets, ep, perm,
                                         Wph, Wpl, bmu, bu, out);
}

// Round 4
// 665.074 us; speedup vs baseline: 1.3439x; 1.3439x over previous
//
#include <hip/hip_runtime.h>

// Problem constants (fixed by the reference file).
#define BN 2
#define NN 50000
#define EE 500000
#define DD 128
#define OO 128

typedef float f2v __attribute__((ext_vector_type(2)));
typedef __attribute__((ext_vector_type(8))) __bf16 bf16x8;
typedef __attribute__((ext_vector_type(4))) float f32x4;

// ---------------------------------------------------------------------------
// prep_k: grid-partitioned fusion of two INDEPENDENT jobs (saves a launch):
//   blocks [0, 193):    Wf = W_msg @ W_upd -> split bf16 hi/lo in MFMA
//                       B-fragment layout; bmu = b_msg @ W_upd. (2 k-rows/blk)
//   blocks [193, 2147): histogram of dst degrees (atomics into hist).
// Fragment layout: idx = ((kstep*8 + coltile)*64 + lane)*8 + e,
//   lane = (k%32/8)*16 + (o%16), e = k%8, kstep = k/32, coltile = o/16.
// ---------------------------------------------------------------------------
#define WBLK 193
__global__ __launch_bounds__(256) void prep_k(
    const float* __restrict__ Wm, const float* __restrict__ Wu,
    const float* __restrict__ bm, unsigned short* __restrict__ Wph,
    unsigned short* __restrict__ Wpl, float* __restrict__ bmu,
    const int* __restrict__ ei, int* __restrict__ hist) {
    if (blockIdx.x < WBLK) {
        const int k = blockIdx.x * 2 + (threadIdx.x >> 7);
        const int o = threadIdx.x & 127;
        if (k > 3 * DD) return;
        float s = 0.0f;
        if (k < 3 * DD) {
#pragma unroll 4
            for (int j = 0; j < OO; ++j) s += Wm[k * OO + j] * Wu[j * OO + o];
            // exact split: s = hi + lo + O(2^-14 * s)
            const unsigned int u = __float_as_uint(s);
            const unsigned short hi = (unsigned short)(u >> 16);
            const float r = s - __uint_as_float(u & 0xffff0000u);
            const unsigned short lo = (unsigned short)(__float_as_uint(r) >> 16);
            const int kstep = k >> 5;
            const int kr = k & 31;
            const int lane = (kr >> 3) * 16 + (o & 15);
            const int ct = o >> 4;
            const int idx = (((kstep * 8) + ct) * 64 + lane) * 8 + (kr & 7);
            Wph[idx] = hi;
            Wpl[idx] = lo;
        } else {
#pragma unroll 4
            for (int j = 0; j < OO; ++j) s += bm[j] * Wu[j * OO + o];
            bmu[o] = s;
        }
    } else {
        const int gid = (blockIdx.x - WBLK) * 256 + threadIdx.x;
        if (gid >= EE) return;
        atomicAdd(&hist[ei[EE + gid]], 1);
    }
}

// ---------------------------------------------------------------------------
// scan_k: single-block (1024 threads) exclusive scan of hist[0..NN) into
// offsets + cursor. Two-pass per thread (49 elems each; 2nd read L2-hot)
// to avoid runtime-indexed register arrays (-> scratch, rule #20).
// Replaces the previous 3-kernel scan cascade.
// ---------------------------------------------------------------------------
__global__ __launch_bounds__(1024) void scan_k(const int* __restrict__ hist,
                                               int* __restrict__ offsets,
                                               int* __restrict__ cursor) {
    __shared__ int s[1024];
    const int t = threadIdx.x;
    const int base = t * 49;
    int tot = 0;
    for (int u = 0; u < 49; ++u) {
        const int i = base + u;
        tot += (i < NN) ? hist[i] : 0;
    }
    s[t] = tot;
    __syncthreads();
    for (int off = 1; off < 1024; off <<= 1) {
        int u = (t >= off) ? s[t - off] : 0;
        __syncthreads();
        s[t] += u;
        __syncthreads();
    }
    int run = s[t] - tot;  // exclusive prefix of this thread's chunk
    for (int u = 0; u < 49; ++u) {
        const int i = base + u;
        if (i < NN) {
            offsets[i] = run;
            cursor[i] = run;
            run += hist[i];
        }
    }
    if (t == 0) offsets[NN] = EE;
}

__global__ __launch_bounds__(256) void fill_k(const int* __restrict__ ei,
                                              int* __restrict__ cursor,
                                              int2* __restrict__ ep) {
    int gid = blockIdx.x * 256 + threadIdx.x;
    if (gid >= EE) return;
    int dst = ei[EE + gid];
    int pos = atomicAdd(&cursor[dst], 1);
    ep[pos] = make_int2(gid, ei[gid]);
}

// ---------------------------------------------------------------------------
// Gather-aggregate: one wave per dst node, lane owns float2. Unroll x4.
// ea streamed with nontemporal loads (protect x's LLC residency).
// (Byte-identical to the round-1 version that measured ~<152 us.)
// ---------------------------------------------------------------------------
__global__ __launch_bounds__(256) void agg_k(
    const float* __restrict__ x,      // (BN, NN, DD)
    const float* __restrict__ ea,     // (EE, DD)
    const int* __restrict__ offsets,  // (NN+1)
    const int2* __restrict__ ep,      // (EE) {edge, src}
    float* __restrict__ S,            // (BN, NN, DD)
    float* __restrict__ T,            // (NN, DD)
    float* __restrict__ cnt)          // (NN)
{
    const int n = (blockIdx.x * 256 + threadIdx.x) >> 6;
    if (n >= NN) return;
    const int lane = threadIdx.x & 63;

    const int beg = offsets[n];
    const int end = offsets[n + 1];

    f2v tA = {0, 0}, s0A = {0, 0}, s1A = {0, 0};

    int j = beg;
    for (; j + 3 < end; j += 4) {
        int2 p0 = ep[j], p1 = ep[j + 1], p2 = ep[j + 2], p3 = ep[j + 3];
        f2v v0 = __builtin_nontemporal_load((const f2v*)(ea + (size_t)p0.x * DD) + lane);
        f2v v1 = __builtin_nontemporal_load((const f2v*)(ea + (size_t)p1.x * DD) + lane);
        f2v v2 = __builtin_nontemporal_load((const f2v*)(ea + (size_t)p2.x * DD) + lane);
        f2v v3 = __builtin_nontemporal_load((const f2v*)(ea + (size_t)p3.x * DD) + lane);
        f2v a0 = ((const f2v*)(x + (size_t)p0.y * DD))[lane];
        f2v a1 = ((const f2v*)(x + (size_t)p1.y * DD))[lane];
        f2v a2 = ((const f2v*)(x + (size_t)p2.y * DD))[lane];
        f2v a3 = ((const f2v*)(x + (size_t)p3.y * DD))[lane];
        f2v b0 = ((const f2v*)(x + ((size_t)NN + p0.y) * DD))[lane];
        f2v b1 = ((const f2v*)(x + ((size_t)NN + p1.y) * DD))[lane];
        f2v b2 = ((const f2v*)(x + ((size_t)NN + p2.y) * DD))[lane];
        f2v b3 = ((const f2v*)(x + ((size_t)NN + p3.y) * DD))[lane];
        tA  += v0 + v1 + v2 + v3;
        s0A += a0 + a1 + a2 + a3;
        s1A += b0 + b1 + b2 + b3;
    }
    for (; j < end; ++j) {
        int2 p = ep[j];
        f2v v = __builtin_nontemporal_load((const f2v*)(ea + (size_t)p.x * DD) + lane);
        f2v a = ((const f2v*)(x + (size_t)p.y * DD))[lane];
        f2v b = ((const f2v*)(x + ((size_t)NN + p.y) * DD))[lane];
        tA += v; s0A += a; s1A += b;
    }

    ((f2v*)(T + (size_t)n * DD))[lane] = tA;
    ((f2v*)(S + (size_t)n * DD))[lane] = s0A;
    ((f2v*)(S + ((size_t)NN + n) * DD))[lane] = s1A;
    if (lane == 0) cnt[n] = (float)(end - beg);
}

// ---------------------------------------------------------------------------
// MFMA GEMM: out = diag(1/max(c,1)) * (A @ Wf) + (c>0)*bmu + bu
// A = [S | c*x | T] (100000 x 384), built on the fly per 128-K chunk
// (chunk == segment). Split-bf16 3-term MFMA (hi*hi + lo*hi + hi*lo).
// Byte-identical to the round-1 version (~74 us, verified).
// ---------------------------------------------------------------------------
__global__ __launch_bounds__(256, 4) void gemm_k(
    const float* __restrict__ S,
    const float* __restrict__ T,
    const float* __restrict__ cnt,
    const float* __restrict__ x,
    const unsigned short* __restrict__ Wph,  // packed bf16-hi frags
    const unsigned short* __restrict__ Wpl,  // packed bf16-lo frags
    const float* __restrict__ bmu,           // (128,)
    const float* __restrict__ bu,            // (128,)
    float* __restrict__ out)                 // (BN*NN, 128)
{
    __shared__ unsigned short Ahi[64 * 128];  // 16 KB
    __shared__ unsigned short Alo[64 * 128];  // 16 KB

    const int tid = threadIdx.x;
    const int R0 = blockIdx.x * 64;
    const int wv = tid >> 6;    // wave id 0..3 -> cols wv*32..+32
    const int l = tid & 63;

    // staging map: 4 threads per row, 32 consecutive k each
    const int srow = tid >> 2;
    const int skq = (tid & 3) * 32;
    const int Rs = R0 + srow;
    const bool sv = Rs < BN * NN;
    const int ns = sv ? (Rs < NN ? Rs : Rs - NN) : 0;
    const int swz = (srow & 7) << 4;
    const float cs = sv ? cnt[ns] : 0.0f;

    f32x4 acc[4][2];
#pragma unroll
    for (int i = 0; i < 4; ++i) {
        acc[i][0] = (f32x4){0.0f, 0.0f, 0.0f, 0.0f};
        acc[i][1] = (f32x4){0.0f, 0.0f, 0.0f, 0.0f};
    }

    for (int seg = 0; seg < 3; ++seg) {
        // ---- stage A chunk (64 rows x 128 k) as bf16 hi/lo into LDS ----
        const float4* p = nullptr;
        if (sv) {
            p = (seg == 0) ? (const float4*)(S + (size_t)Rs * DD + skq)
              : (seg == 1) ? (const float4*)(x + (size_t)Rs * DD + skq)
                           : (const float4*)(T + (size_t)ns * DD + skq);
        }
#pragma unroll
        for (int j = 0; j < 4; ++j) {
            float4 u0 = {0, 0, 0, 0}, u1 = {0, 0, 0, 0};
            if (sv) {
                u0 = p[2 * j];
                u1 = p[2 * j + 1];
                if (seg == 1) {
                    u0.x *= cs; u0.y *= cs; u0.z *= cs; u0.w *= cs;
                    u1.x *= cs; u1.y *= cs; u1.z *= cs; u1.w *= cs;
                }
            }
            const float vv[8] = {u0.x, u0.y, u0.z, u0.w, u1.x, u1.y, u1.z, u1.w};
            unsigned int hw[4], lw[4];
#pragma unroll
            for (int i = 0; i < 4; ++i) {
                const unsigned int b0 = __float_as_uint(vv[2 * i]);
                const unsigned int b1 = __float_as_uint(vv[2 * i + 1]);
                const float r0 = vv[2 * i]     - __uint_as_float(b0 & 0xffff0000u);
                const float r1 = vv[2 * i + 1] - __uint_as_float(b1 & 0xffff0000u);
                hw[i] = (b0 >> 16) | (b1 & 0xffff0000u);
                lw[i] = (__float_as_uint(r0) >> 16) | (__float_as_uint(r1) & 0xffff0000u);
            }
            const int byt = srow * 256 + (((skq + j * 8) * 2) ^ swz);
            *(int4*)((char*)Ahi + byt) = make_int4(hw[0], hw[1], hw[2], hw[3]);
            *(int4*)((char*)Alo + byt) = make_int4(lw[0], lw[1], lw[2], lw[3]);
        }
        __syncthreads();

        // ---- compute: 4 MFMA k-steps of 32 over this chunk ----
#pragma unroll
        for (int ks = 0; ks < 4; ++ks) {
            bf16x8 ah[4], al[4];
#pragma unroll
            for (int rt = 0; rt < 4; ++rt) {
                const int row = rt * 16 + (l & 15);
                const int rb = row * 256 +
                               ((ks * 64 + (l >> 4) * 16) ^ ((row & 7) << 4));
                ah[rt] = *(const bf16x8*)((const char*)Ahi + rb);
                al[rt] = *(const bf16x8*)((const char*)Alo + rb);
            }
            const int kg = seg * 4 + ks;
#pragma unroll
            for (int ct = 0; ct < 2; ++ct) {
                const size_t fi =
                    (size_t)(((kg * 8) + (wv * 2 + ct)) * 64 + l) * 8;
                const bf16x8 wh = *(const bf16x8*)(Wph + fi);
                const bf16x8 wl = *(const bf16x8*)(Wpl + fi);
#pragma unroll
                for (int rt = 0; rt < 4; ++rt) {
                    acc[rt][ct] = __builtin_amdgcn_mfma_f32_16x16x32_bf16(
                        ah[rt], wh, acc[rt][ct], 0, 0, 0);
                    acc[rt][ct] = __builtin_amdgcn_mfma_f32_16x16x32_bf16(
                        al[rt], wh, acc[rt][ct], 0, 0, 0);
                    acc[rt][ct] = __builtin_amdgcn_mfma_f32_16x16x32_bf16(
                        ah[rt], wl, acc[rt][ct], 0, 0, 0);
                }
            }
        }
        __syncthreads();
    }

    // ---- epilogue ----
    const int col0 = wv * 32 + (l & 15);
    const float bm0 = bmu[col0], bm1 = bmu[col0 + 16];
    const float bu0 = bu[col0], bu1 = bu[col0 + 16];
    const int rbase = (l >> 4) * 4;
#pragma unroll
    for (int rt = 0; rt < 4; ++rt) {
#pragma unroll
        for (int r = 0; r < 4; ++r) {
            const int Rr = R0 + rt * 16 + rbase + r;
            if (Rr < BN * NN) {
                const int nr = (Rr < NN) ? Rr : Rr - NN;
                const float c = cnt[nr];
                const float inv = 1.0f / fmaxf(c, 1.0f);
                const float g = (c > 0.0f) ? 1.0f : 0.0f;
                __builtin_nontemporal_store(
                    acc[rt][0][r] * inv + g * bm0 + bu0,
                    out + (size_t)Rr * OO + col0);
                __builtin_nontemporal_store(
                    acc[rt][1][r] * inv + g * bm1 + bu1,
                    out + (size_t)Rr * OO + col0 + 16);
            }
        }
    }
}

extern "C" void kernel_launch(void* const* d_in, const int* in_sizes, int n_in,
                              void* d_out, int out_size, void* d_ws, size_t ws_size,
                              hipStream_t stream) {
    const float* x  = (const float*)d_in[0];
    const int*   ei = (const int*)d_in[1];
    const float* ea = (const float*)d_in[2];
    const float* Wm = (const float*)d_in[3];
    const float* bm = (const float*)d_in[4];
    const float* Wu = (const float*)d_in[5];
    const float* bu = (const float*)d_in[6];
    float* out = (float*)d_out;

    // workspace layout
    float* S   = (float*)d_ws;                        // 12,800,000 f
    float* T   = S + (size_t)BN * NN * DD;            //  6,400,000 f
    float* cnt = T + (size_t)NN * DD;                 //     50,000 f
    float* bmu = cnt + NN;                            //        128 f
    unsigned short* Wph = (unsigned short*)(bmu + OO);//     49,152 us
    unsigned short* Wpl = Wph + 3 * DD * OO;          //     49,152 us
    int* offsets = (int*)(Wpl + 3 * DD * OO);         //     50,004 i
    int* cursor  = offsets + 50004;                   //     50,000 i
    int* hist    = cursor + NN;                       //     50,000 i
    int2* ep     = (int2*)(hist + NN);                //    500,000 int2

    hipMemsetAsync(hist, 0, NN * sizeof(int), stream);

    const int nhist = (EE + 255) / 256;               // 1954
    prep_k<<<WBLK + nhist, 256, 0, stream>>>(Wm, Wu, bm, Wph, Wpl, bmu,
                                             ei, hist);
    scan_k<<<1, 1024, 0, stream>>>(hist, offsets, cursor);
    fill_k<<<nhist, 256, 0, stream>>>(ei, cursor, ep);

    agg_k<<<(NN + 3) / 4, 256, 0, stream>>>(x, ea, offsets, ep, S, T, cnt);

    const int nblocks = (BN * NN + 63) / 64;
    gemm_k<<<nblocks, 256, 0, stream>>>(S, T, cnt, x, Wph, Wpl, bmu, bu, out);
}